// Round 10
// baseline (1348.954 us; speedup 1.0000x reference)
//
#include <hip/hip_runtime.h>
#include <stdint.h>

#define NN   2048
#define TTT  512
#define NT   (NN * TTT)          /* 1048576 rows */
#define NTM  (NN * (TTT - 1))    /* 1046528 rows */
#define SLOPE 0.01f
#define BN_EPS 1e-5f

typedef unsigned int uint;

/* ---- workspace layout ----
   bytes [0, 28KB)      : fp32 weights + affine (float offsets below)
   bytes [32768, 33792) : stats (192 edge + 64 node floats)
   bytes [36864, 36868) : dtype flag
   bytes [65536, ...)   : edge branch outputs [3][NT][32] fp32 (402 MB) when
                          ws_size permits; else recompute fallback.

   Register-allocator ledger (this toolchain, gfx950):
     no __launch_bounds__      -> VGPR clamped ~64 -> spills big kernels
     __launch_bounds__(256)    -> allocator free (R8: 96 regs, zero spill) <- USE
     __launch_bounds__(256,N)  -> hard caps (N=2 -> ~100, N=4 -> 64) -> spills

   Shape-per-bottleneck ledger:
     edge (weight-stream-bound): 2 rows/thread WINS (610 -> 475 us)
     node (VMEM-latency): 1 row/thread WINS (2-row lost ~110 us)
   Weight-stream ledger:
     SGPR path depth-capped (~112 SGPRs = ~1.5KB in flight) -> R10 streams
     W2/W3 via vector L1 (opaque VGPR offset), W1 stays scalar. */
#define W_EW1   0      /* [33][32] row-major: W1a[16][32], W1b[16][32], dir row */
#define W_EW1C  1056   /* [16][32] combined (W1a+W1b) for inplace branch */
#define W_EB1   1568
#define W_EW2   1600   /* [32][32] */
#define W_EB2   2624
#define W_EW3   2656   /* [32][32] */
#define W_EB3   3680
#define W_NW1   3712   /* [32][32] */
#define W_NB1   4736
#define W_NW2   4768   /* [32][32] */
#define W_NB2   5792
#define W_NW3   5824   /* [32][32] */
#define W_NB3   6848
#define W_AFF   6880   /* [3][64]: per branch scale[32] then shift[32] */

#define WS_EDGE_BYTE_OFF 65536ull
#define EOUT_BR_STRIDE   ((size_t)NT * 32u)   /* floats */

__device__ __forceinline__ float bf2f(uint16_t u) {
    union { uint u32; float f; } v; v.u32 = ((uint)u) << 16; return v.f;
}
__device__ __forceinline__ uint16_t f2bf(float f) {
    union { float f; uint u; } v; v.f = f;
    uint r = v.u + 0x7FFFu + ((v.u >> 16) & 1u);   // RTNE
    return (uint16_t)(r >> 16);
}

template <bool F32>
__device__ __forceinline__ float wv(const void* W, int i) {
    return F32 ? ((const float*)W)[i] : bf2f(((const uint16_t*)W)[i]);
}

template <bool F32>
__device__ __forceinline__ void loadrow16(const void* x, size_t elt, float* f) {
    if (F32) {
        const float4* q = (const float4*)((const float*)x + elt);
        float4 a = q[0], b = q[1], c = q[2], d = q[3];
        f[0]=a.x; f[1]=a.y; f[2]=a.z; f[3]=a.w;
        f[4]=b.x; f[5]=b.y; f[6]=b.z; f[7]=b.w;
        f[8]=c.x; f[9]=c.y; f[10]=c.z; f[11]=c.w;
        f[12]=d.x; f[13]=d.y; f[14]=d.z; f[15]=d.w;
    } else {
        const uint4* q = (const uint4*)((const uint16_t*)x + elt);
        uint4 a = q[0], b = q[1];
        uint w[8] = {a.x, a.y, a.z, a.w, b.x, b.y, b.z, b.w};
#pragma unroll
        for (int i = 0; i < 8; i++) {
            union { uint u; float f; } lo, hi;
            lo.u = w[i] << 16; hi.u = w[i] & 0xFFFF0000u;
            f[2*i] = lo.f; f[2*i+1] = hi.f;
        }
    }
}
template <bool F32>
__device__ __forceinline__ void loadrow32(const void* x, size_t elt, float* f) {
    loadrow16<F32>(x, elt, f); loadrow16<F32>(x, elt + 16, f + 16);
}
template <bool F32>
__device__ __forceinline__ void storerow32(void* out, size_t elt, const float* f) {
    if (F32) {
        float4* q = (float4*)((float*)out + elt);
#pragma unroll
        for (int i = 0; i < 8; i++)
            q[i] = make_float4(f[4*i], f[4*i+1], f[4*i+2], f[4*i+3]);
    } else {
        uint w[16];
#pragma unroll
        for (int i = 0; i < 16; i++)
            w[i] = (uint)f2bf(f[2*i]) | ((uint)f2bf(f[2*i+1]) << 16);
        uint4* q = (uint4*)((uint16_t*)out + elt);
        q[0] = make_uint4(w[0], w[1], w[2], w[3]);
        q[1] = make_uint4(w[4], w[5], w[6], w[7]);
        q[2] = make_uint4(w[8], w[9], w[10], w[11]);
        q[3] = make_uint4(w[12], w[13], w[14], w[15]);
    }
}

// h[j] += sum_i W[i*32+j] * in[i]. Weights via wave-uniform s_load (SMEM).
template <int K>
__device__ __forceinline__ void dense(const float* __restrict__ W, const float* in, float* h) {
#pragma unroll
    for (int i = 0; i < K; i++) {
        const float x = in[i];
        const float4* __restrict__ w4 = (const float4*)(W + i * 32);
#pragma unroll
        for (int j = 0; j < 8; j++) {
            float4 w = w4[j];
            h[4*j+0] = fmaf(w.x, x, h[4*j+0]);
            h[4*j+1] = fmaf(w.y, x, h[4*j+1]);
            h[4*j+2] = fmaf(w.z, x, h[4*j+2]);
            h[4*j+3] = fmaf(w.w, x, h[4*j+3]);
        }
    }
}
// TWO row-streams per weight fetch, scalar (SGPR) weight path.
template <int K>
__device__ __forceinline__ void dense2(const float* __restrict__ W,
    const float* inA, const float* inB, float* hA, float* hB)
{
#pragma unroll
    for (int i = 0; i < K; i++) {
        const float xa = inA[i], xb = inB[i];
        const float4* __restrict__ w4 = (const float4*)(W + i * 32);
#pragma unroll
        for (int j = 0; j < 8; j++) {
            float4 w = w4[j];
            hA[4*j+0] = fmaf(w.x, xa, hA[4*j+0]);
            hA[4*j+1] = fmaf(w.y, xa, hA[4*j+1]);
            hA[4*j+2] = fmaf(w.z, xa, hA[4*j+2]);
            hA[4*j+3] = fmaf(w.w, xa, hA[4*j+3]);
            hB[4*j+0] = fmaf(w.x, xb, hB[4*j+0]);
            hB[4*j+1] = fmaf(w.y, xb, hB[4*j+1]);
            hB[4*j+2] = fmaf(w.z, xb, hB[4*j+2]);
            hB[4*j+3] = fmaf(w.w, xb, hB[4*j+3]);
        }
    }
}
// TWO row-streams, weights via the VECTOR path: the opaque VGPR offset voff
// (runtime 0) makes the address look divergent, so the compiler emits
// global_load_dwordx4 (L1 + deep vmcnt queue) instead of s_load (SGPR file
// capped at ~1.5KB in flight). W1 stays scalar -> two independent latency
// chains + two caches (sK$ for W1, vector L1 for W2/W3).
template <int K>
__device__ __forceinline__ void dense2v(const float* __restrict__ W, uint voff,
    const float* inA, const float* inB, float* hA, float* hB)
{
#pragma unroll
    for (int i = 0; i < K; i++) {
        const float xa = inA[i], xb = inB[i];
        const float4* __restrict__ w4 = (const float4*)(W + i * 32 + voff);
#pragma unroll
        for (int j = 0; j < 8; j++) {
            float4 w = w4[j];
            hA[4*j+0] = fmaf(w.x, xa, hA[4*j+0]);
            hA[4*j+1] = fmaf(w.y, xa, hA[4*j+1]);
            hA[4*j+2] = fmaf(w.z, xa, hA[4*j+2]);
            hA[4*j+3] = fmaf(w.w, xa, hA[4*j+3]);
            hB[4*j+0] = fmaf(w.x, xb, hB[4*j+0]);
            hB[4*j+1] = fmaf(w.y, xb, hB[4*j+1]);
            hB[4*j+2] = fmaf(w.z, xb, hB[4*j+2]);
            hB[4*j+3] = fmaf(w.w, xb, hB[4*j+3]);
        }
    }
}
__device__ __forceinline__ void lrelu32(float* h) {
#pragma unroll
    for (int j = 0; j < 32; j++) h[j] = fmaxf(h[j], h[j] * SLOPE);
}

// One edge branch, ONE row (node recompute fallback only).
template <bool INPLACE>
__device__ __forceinline__ void edge_mlp(
    const float* __restrict__ wts,
    const float* xt, const float* xn, float dir, float* o)
{
    const float* __restrict__ W1  = wts + W_EW1;
    const float* __restrict__ W1c = wts + W_EW1C;
    const float* __restrict__ B1  = wts + W_EB1;
    const float* __restrict__ W2  = wts + W_EW2;
    const float* __restrict__ B2  = wts + W_EB2;
    const float* __restrict__ W3  = wts + W_EW3;
    const float* __restrict__ B3  = wts + W_EB3;

    float h1[32];
#pragma unroll
    for (int j = 0; j < 32; j++) h1[j] = fmaf(dir, W1[1024 + j], B1[j]);
    if (INPLACE) {
        dense<16>(W1c, xt, h1);
    } else {
        dense<16>(W1, xt, h1);
        dense<16>(W1 + 512, xn, h1);
    }
    lrelu32(h1);
    float h2[32];
#pragma unroll
    for (int j = 0; j < 32; j++) h2[j] = B2[j];
    dense<32>(W2, h1, h2);
    lrelu32(h2);
#pragma unroll
    for (int j = 0; j < 32; j++) o[j] = B3[j];
    dense<32>(W3, h2, o);
}

// One edge branch, TWO adjacent rows (r0 even); W2/W3 via vector path.
template <int MODE>
__device__ __forceinline__ void edge2_mlp(
    const float* __restrict__ wts, uint voff,
    const float* xA, const float* xB, const float* xE,
    float* oA, float* oB)
{
    const float* __restrict__ W1a = wts + W_EW1;
    const float* __restrict__ W1b = wts + W_EW1 + 512;
    const float* __restrict__ WD  = wts + W_EW1 + 1024;
    const float* __restrict__ W1c = wts + W_EW1C;
    const float* __restrict__ B1  = wts + W_EB1;
    const float* __restrict__ W2  = wts + W_EW2;
    const float* __restrict__ B2  = wts + W_EB2;
    const float* __restrict__ W3  = wts + W_EW3;
    const float* __restrict__ B3  = wts + W_EB3;
    const float dir = (MODE == 0) ? 0.f : (MODE == 1) ? 1.f : -1.f;

    float hA[32], hB[32];
#pragma unroll
    for (int j = 0; j < 32; j++) {
        float v = fmaf(dir, WD[j], B1[j]);
        hA[j] = v; hB[j] = v;
    }
    if (MODE == 0) {
        dense2<16>(W1c, xA, xB, hA, hB);
    } else if (MODE == 1) {
        dense2<16>(W1a, xA, xB, hA, hB);
        dense2<16>(W1b, xE, xA, hA, hB);
    } else {
        dense2<16>(W1a, xA, xB, hA, hB);
        dense2<16>(W1b, xB, xE, hA, hB);
    }
    lrelu32(hA); lrelu32(hB);

    float gA[32], gB[32];
#pragma unroll
    for (int j = 0; j < 32; j++) { float b = B2[j]; gA[j] = b; gB[j] = b; }
    dense2v<32>(W2, voff, hA, hB, gA, gB);
    lrelu32(gA); lrelu32(gB);

#pragma unroll
    for (int j = 0; j < 32; j++) { float b = B3[j]; oA[j] = b; oB[j] = b; }
    dense2v<32>(W3, voff, gA, gB, oA, oB);
}

// Packed in-place reduce-scatter butterfly: sums v[j] and v[j]^2 over 64 lanes.
// DESTROYS v. lane L<32 -> sum of channel L; lane L>=32 -> sumsq of ch L-32.
__device__ __forceinline__ float stats_reduce64(float* v, int lane) {
    const bool hi = lane >= 32;
#pragma unroll
    for (int j = 0; j < 32; j++) {
        float s = v[j], q = v[j] * v[j];
        float r = __shfl_xor(hi ? s : q, 32, 64);
        v[j] = (hi ? q : s) + r;
    }
#pragma unroll
    for (int m = 16; m >= 1; m >>= 1) {
        const bool b = (lane & m) != 0;
#pragma unroll
        for (int j = 0; j < m; j++) {
            float r = __shfl_xor(b ? v[j] : v[j + m], m, 64);
            v[j] = (b ? v[j + m] : v[j]) + r;
        }
    }
    return v[0];
}
// Two-row variant: folds A+B / A^2+B^2 in the first sweep. DESTROYS a.
__device__ __forceinline__ float stats_reduce64_pair(float* a, const float* b, int lane) {
    const bool hi = lane >= 32;
#pragma unroll
    for (int j = 0; j < 32; j++) {
        float s = a[j] + b[j];
        float q = a[j] * a[j] + b[j] * b[j];
        float r = __shfl_xor(hi ? s : q, 32, 64);
        a[j] = (hi ? q : s) + r;
    }
#pragma unroll
    for (int m = 16; m >= 1; m >>= 1) {
        const bool bb = (lane & m) != 0;
#pragma unroll
        for (int j = 0; j < m; j++) {
            float r = __shfl_xor(bb ? a[j] : a[j + m], m, 64);
            a[j] = (bb ? a[j + m] : a[j]) + r;
        }
    }
    return a[0];
}

// ---------------- prep: dtype detect + fp32 weight conversion ----------------
__global__ void prep_kernel(
    const uint* __restrict__ x,
    const void* __restrict__ eW1, const void* __restrict__ eb1,
    const void* __restrict__ eW2, const void* __restrict__ eb2,
    const void* __restrict__ eW3, const void* __restrict__ eb3,
    const void* __restrict__ nW1, const void* __restrict__ nb1,
    const void* __restrict__ nW2, const void* __restrict__ nb2,
    const void* __restrict__ nW3, const void* __restrict__ nb3,
    int* __restrict__ flag, float* __restrict__ wts)
{
    __shared__ int cnt;
    const int tid = threadIdx.x;
    if (tid == 0) cnt = 0;
    __syncthreads();
    if (tid < 64) {
        uint w = x[tid];
        uint e = (w >> 7) & 0xFFu;
        if (e >= 110u && e <= 134u) atomicAdd(&cnt, 1);
    }
    __syncthreads();
    const bool f32 = (cnt < 32);
    if (tid == 0) flag[0] = f32 ? 1 : 0;
    auto rd = [&](const void* p, int i) -> float {
        return f32 ? ((const float*)p)[i] : bf2f(((const uint16_t*)p)[i]);
    };
    for (int i = tid; i < 1056; i += 256) wts[W_EW1 + i] = rd(eW1, i);
    for (int i = tid; i < 512;  i += 256) wts[W_EW1C + i] = rd(eW1, i) + rd(eW1, 512 + i);
    for (int i = tid; i < 1024; i += 256) {
        wts[W_EW2 + i] = rd(eW2, i); wts[W_EW3 + i] = rd(eW3, i);
        wts[W_NW1 + i] = rd(nW1, i); wts[W_NW2 + i] = rd(nW2, i); wts[W_NW3 + i] = rd(nW3, i);
    }
    if (tid < 32) {
        wts[W_EB1 + tid] = rd(eb1, tid); wts[W_EB2 + tid] = rd(eb2, tid); wts[W_EB3 + tid] = rd(eb3, tid);
        wts[W_NB1 + tid] = rd(nb1, tid); wts[W_NB2 + tid] = rd(nb2, tid); wts[W_NB3 + tid] = rd(nb3, tid);
    }
}

// ------- pass 1: one branch per block, 2 rows per thread, XCD-interleaved -------
template <bool F32, bool STORE>
__global__ __launch_bounds__(256) void edge_branch2_kernel(
    const void* __restrict__ x, const float* __restrict__ wts,
    const int* __restrict__ flag, float* __restrict__ gstats /*192*/,
    float* __restrict__ eout)
{
    if ((flag[0] != 0) != F32) return;
    __shared__ float sSt[64];
    const int tid = threadIdx.x;
    const int lane = tid & 63;
    const uint bid = blockIdx.x;           // 0 .. 3*NT/512-1
    const uint unit = bid / 24u;
    const uint inner = bid % 24u;
    const int  by = (int)(inner >> 3);     // branch: 0 inpl, 1 fwd, 2 bwd
    const uint bx = unit * 8u + (inner & 7u);
    if (tid < 64) sSt[tid] = 0.f;
    __syncthreads();

    // opaque zero in a VGPR: forces W2/W3 reads onto the vector-memory path
    uint voff = 0;
    asm volatile("" : "+v"(voff));

    const uint r0 = bx * 512u + (uint)tid * 2u;   // even row; rows r0, r0+1
    const uint t0 = r0 & 511u;                     // even, <= 510

    float xA[16], xB[16];
    loadrow16<F32>(x, (size_t)r0 << 4, xA);
    loadrow16<F32>(x, (size_t)(r0 + 1u) << 4, xB);

    float oA[32], oB[32];
    float vfA = 1.f, vfB = 1.f;
    if (by == 0) {
        edge2_mlp<0>(wts, voff, xA, xB, xA, oA, oB);
    } else if (by == 1) {
        const uint rp = (t0 > 0u) ? r0 - 1u : r0;
        float xP[16]; loadrow16<F32>(x, (size_t)rp << 4, xP);
        edge2_mlp<1>(wts, voff, xA, xB, xP, oA, oB);
        vfA = (t0 > 0u) ? 1.f : 0.f;
    } else {
        const uint rn = (t0 != 510u) ? r0 + 2u : r0 + 1u;
        float xN[16]; loadrow16<F32>(x, (size_t)rn << 4, xN);
        edge2_mlp<2>(wts, voff, xA, xB, xN, oA, oB);
        vfB = (t0 != 510u) ? 1.f : 0.f;
    }

    if (STORE) {
        const size_t base = (size_t)by * EOUT_BR_STRIDE + (size_t)r0 * 32u;
        storerow32<true>((void*)eout, base, oA);
        storerow32<true>((void*)eout, base + 32u, oB);
    }
#pragma unroll
    for (int j = 0; j < 32; j++) { oA[j] *= vfA; oB[j] *= vfB; }
    atomicAdd(&sSt[lane], stats_reduce64_pair(oA, oB, lane));
    __syncthreads();
    if (tid < 64) atomicAdd(&gstats[by * 64 + tid], sSt[tid]);
}

// ------------- tiny: edge BN affine coefficients -> workspace (SGPR path) -------------
template <bool F32>
__global__ void edge_affine_kernel(
    const float* __restrict__ gstats_edge,
    const void* __restrict__ egamma, const void* __restrict__ ebeta,
    const int* __restrict__ flag, float* __restrict__ wts_aff)
{
    if ((flag[0] != 0) != F32) return;
    const int tid = threadIdx.x;
    if (tid < 32) {
        float g = wv<F32>(egamma, tid), be = wv<F32>(ebeta, tid);
#pragma unroll
        for (int br = 0; br < 3; br++) {
            float cnt = (br == 0) ? (float)NT : (float)NTM;
            float s = gstats_edge[br * 64 + tid], q = gstats_edge[br * 64 + 32 + tid];
            float mu = s / cnt;
            float var = q / cnt - mu * mu;
            float sc = g * rsqrtf(var + BN_EPS);
            wts_aff[W_AFF + br * 64 + tid] = sc;
            wts_aff[W_AFF + br * 64 + 32 + tid] = be - mu * sc;
        }
    }
}

// -------- pass 2 (stored): ONE row/thread: load branch outputs, affine, node MLP --------
template <bool F32>
__global__ __launch_bounds__(256) void node_store_kernel(
    const float* __restrict__ eout, const float* __restrict__ wts,
    const int* __restrict__ flag, float* __restrict__ gstats_node,
    void* __restrict__ out)
{
    if ((flag[0] != 0) != F32) return;
    __shared__ float sSt[64];
    const int tid = threadIdx.x;
    const int lane = tid & 63;
    if (tid < 64) sSt[tid] = 0.f;
    __syncthreads();

    const float* __restrict__ AFF = wts + W_AFF;
    const uint r = blockIdx.x * 256u + (uint)tid;
    const uint t = r & 511u;
    const float vf0 = (t > 0u) ? 1.f : 0.f;
    const float vf1 = (t < 511u) ? 1.f : 0.f;

    float agg[32], ob[32];
    loadrow32<true>((const void*)eout, (size_t)r * 32u, ob);
#pragma unroll
    for (int j = 0; j < 32; j++) agg[j] = fmaf(AFF[j], ob[j], AFF[32 + j]);
    loadrow32<true>((const void*)eout, EOUT_BR_STRIDE + (size_t)r * 32u, ob);
#pragma unroll
    for (int j = 0; j < 32; j++) agg[j] += vf0 * fmaf(AFF[64 + j], ob[j], AFF[96 + j]);
    loadrow32<true>((const void*)eout, 2u * EOUT_BR_STRIDE + (size_t)r * 32u, ob);
#pragma unroll
    for (int j = 0; j < 32; j++) agg[j] += vf1 * fmaf(AFF[128 + j], ob[j], AFF[160 + j]);

    const float* __restrict__ NW1 = wts + W_NW1;
    const float* __restrict__ NW2 = wts + W_NW2;
    const float* __restrict__ NW3 = wts + W_NW3;
    const float* __restrict__ NB1 = wts + W_NB1;
    const float* __restrict__ NB2 = wts + W_NB2;
    const float* __restrict__ NB3 = wts + W_NB3;

    float g1[32];
#pragma unroll
    for (int j = 0; j < 32; j++) g1[j] = NB1[j];
    dense<32>(NW1, agg, g1);
    lrelu32(g1);
    float g2[32];
#pragma unroll
    for (int j = 0; j < 32; j++) g2[j] = NB2[j];
    dense<32>(NW2, g1, g2);
    lrelu32(g2);
    float g3[32];
#pragma unroll
    for (int j = 0; j < 32; j++) g3[j] = NB3[j];
    dense<32>(NW3, g2, g3);

    storerow32<F32>(out, (size_t)r * 32u, g3);
    atomicAdd(&sSt[lane], stats_reduce64(g3, lane));   // destroys g3 (already stored)
    __syncthreads();
    if (tid < 64) atomicAdd(&gstats_node[tid], sSt[tid]);
}

// -------- pass 2 (fallback, ws too small): recompute branches, 1 row --------
template <bool F32>
__global__ __launch_bounds__(256) void node_recompute_kernel(
    const void* __restrict__ x, const float* __restrict__ wts,
    const int* __restrict__ flag, float* __restrict__ gstats_node,
    void* __restrict__ out)
{
    if ((flag[0] != 0) != F32) return;
    __shared__ float sSt[64];
    const int tid = threadIdx.x;
    const int lane = tid & 63;
    if (tid < 64) sSt[tid] = 0.f;
    __syncthreads();

    const float* __restrict__ AFF = wts + W_AFF;
    const uint r = blockIdx.x * 256u + (uint)tid;
    const uint t = r & 511u;
    float xt[16]; loadrow16<F32>(x, (size_t)r << 4, xt);
    float agg[32], o[32];

    edge_mlp<true>(wts, xt, xt, 0.f, o);
#pragma unroll
    for (int j = 0; j < 32; j++) agg[j] = fmaf(AFF[j], o[j], AFF[32 + j]);
    {
        const float vf = (t > 0u) ? 1.f : 0.f;
        const uint rn = (t > 0u) ? r - 1u : r;
        float xn[16]; loadrow16<F32>(x, (size_t)rn << 4, xn);
        edge_mlp<false>(wts, xt, xn, 1.f, o);
#pragma unroll
        for (int j = 0; j < 32; j++) agg[j] += vf * fmaf(AFF[64 + j], o[j], AFF[96 + j]);
    }
    {
        const float vf = (t < 511u) ? 1.f : 0.f;
        const uint rn = (t < 511u) ? r + 1u : r;
        float xn[16]; loadrow16<F32>(x, (size_t)rn << 4, xn);
        edge_mlp<false>(wts, xt, xn, -1.f, o);
#pragma unroll
        for (int j = 0; j < 32; j++) agg[j] += vf * fmaf(AFF[128 + j], o[j], AFF[160 + j]);
    }

    const float* __restrict__ NW1 = wts + W_NW1;
    const float* __restrict__ NW2 = wts + W_NW2;
    const float* __restrict__ NW3 = wts + W_NW3;
    const float* __restrict__ NB1 = wts + W_NB1;
    const float* __restrict__ NB2 = wts + W_NB2;
    const float* __restrict__ NB3 = wts + W_NB3;

    float g1[32];
#pragma unroll
    for (int j = 0; j < 32; j++) g1[j] = NB1[j];
    dense<32>(NW1, agg, g1);
    lrelu32(g1);
    float g2[32];
#pragma unroll
    for (int j = 0; j < 32; j++) g2[j] = NB2[j];
    dense<32>(NW2, g1, g2);
    lrelu32(g2);
    float g3[32];
#pragma unroll
    for (int j = 0; j < 32; j++) g3[j] = NB3[j];
    dense<32>(NW3, g2, g3);

    storerow32<F32>(out, (size_t)r * 32u, g3);
    atomicAdd(&sSt[lane], stats_reduce64(g3, lane));
    __syncthreads();
    if (tid < 64) atomicAdd(&gstats_node[tid], sSt[tid]);
}

// ---------------- pass 3: in-place node BN affine ----------------
template <bool F32>
__global__ __launch_bounds__(256) void finalize_kernel(
    const float* __restrict__ gstats_node,
    const void* __restrict__ ngamma, const void* __restrict__ nbeta,
    const int* __restrict__ flag, void* __restrict__ out)
{
    if ((flag[0] != 0) != F32) return;
    __shared__ float sc[32], sh[32];
    const int tid = threadIdx.x;
    if (tid < 32) {
        float s = gstats_node[tid], q = gstats_node[32 + tid];
        float mu = s / (float)NT;
        float var = q / (float)NT - mu * mu;
        float k = wv<F32>(ngamma, tid) * rsqrtf(var + BN_EPS);
        sc[tid] = k; sh[tid] = wv<F32>(nbeta, tid) - mu * k;
    }
    __syncthreads();
    const uint r = blockIdx.x * 256u + (uint)tid;
    float v[32]; loadrow32<F32>(out, (size_t)r * 32u, v);
    float o[32];
#pragma unroll
    for (int j = 0; j < 32; j++) o[j] = fmaf(sc[j], v[j], sh[j]);
    storerow32<F32>(out, (size_t)r * 32u, o);
}

extern "C" void kernel_launch(void* const* d_in, const int* in_sizes, int n_in,
                              void* d_out, int out_size, void* d_ws, size_t ws_size,
                              hipStream_t stream) {
    const void* x   = d_in[0];
    const void* eW1 = d_in[1]; const void* eb1 = d_in[2];
    const void* eW2 = d_in[3]; const void* eb2 = d_in[4];
    const void* eW3 = d_in[5]; const void* eb3 = d_in[6];
    const void* eg  = d_in[7]; const void* ebt = d_in[8];
    const void* nW1 = d_in[9]; const void* nb1 = d_in[10];
    const void* nW2 = d_in[11]; const void* nb2 = d_in[12];
    const void* nW3 = d_in[13]; const void* nb3 = d_in[14];
    const void* ng  = d_in[15]; const void* nbt = d_in[16];

    float* wts   = (float*)d_ws;                       // fp32 weights + affine
    float* stats = (float*)((char*)d_ws + 32768);      // [0..191] edge, [192..255] node
    int* flag    = (int*)((char*)d_ws + 36864);        // dtype flag: 1 = fp32, 0 = bf16
    float* eout  = (float*)((char*)d_ws + WS_EDGE_BYTE_OFF);

    const size_t need = WS_EDGE_BYTE_OFF + 3ull * (size_t)NT * 32ull * sizeof(float);
    const bool stored = (ws_size >= need);

    hipMemsetAsync((char*)d_ws + 32768, 0, 8192, stream);
    prep_kernel<<<dim3(1), dim3(256), 0, stream>>>((const uint*)x,
        eW1, eb1, eW2, eb2, eW3, eb3, nW1, nb1, nW2, nb2, nW3, nb3, flag, wts);

    dim3 blk(256);
    dim3 egrid(3 * (NT / 512));      // edge: 2 rows/thread
    dim3 fgrid(NT / 256);            // node/finalize: 1 row/thread
    if (stored) {
        edge_branch2_kernel<true,  true><<<egrid, blk, 0, stream>>>(x, wts, flag, stats, eout);
        edge_branch2_kernel<false, true><<<egrid, blk, 0, stream>>>(x, wts, flag, stats, eout);
    } else {
        edge_branch2_kernel<true,  false><<<egrid, blk, 0, stream>>>(x, wts, flag, stats, eout);
        edge_branch2_kernel<false, false><<<egrid, blk, 0, stream>>>(x, wts, flag, stats, eout);
    }
    edge_affine_kernel<true><<<dim3(1), dim3(64), 0, stream>>>(stats, eg, ebt, flag, wts);
    edge_affine_kernel<false><<<dim3(1), dim3(64), 0, stream>>>(stats, eg, ebt, flag, wts);
    if (stored) {
        node_store_kernel<true><<<fgrid, blk, 0, stream>>>(eout, wts, flag, stats + 192, d_out);
        node_store_kernel<false><<<fgrid, blk, 0, stream>>>(eout, wts, flag, stats + 192, d_out);
    } else {
        node_recompute_kernel<true><<<fgrid, blk, 0, stream>>>(x, wts, flag, stats + 192, d_out);
        node_recompute_kernel<false><<<fgrid, blk, 0, stream>>>(x, wts, flag, stats + 192, d_out);
    }
    finalize_kernel<true><<<fgrid, blk, 0, stream>>>(stats + 192, ng, nbt, flag, d_out);
    finalize_kernel<false><<<fgrid, blk, 0, stream>>>(stats + 192, ng, nbt, flag, d_out);
}

// Round 11
// 877.567 us; speedup vs baseline: 1.5372x; 1.5372x over previous
//
#include <hip/hip_runtime.h>
#include <stdint.h>

#define NN   2048
#define TTT  512
#define NT   (NN * TTT)          /* 1048576 rows */
#define NTM  (NN * (TTT - 1))    /* 1046528 rows */
#define SLOPE 0.01f
#define BN_EPS 1e-5f

typedef unsigned int uint;
typedef float v2 __attribute__((ext_vector_type(2)));

/* ---- workspace layout ----
   bytes [0, 28KB)      : fp32 weights + affine (float offsets below)
   bytes [32768, 33792) : stats (192 edge + 64 node floats)
   bytes [36864, 36868) : dtype flag
   bytes [65536, ...)   : edge branch outputs [3][NT][32] fp32 (402 MB) when
                          ws_size permits; else recompute fallback.

   Register-allocator ledger (this toolchain, gfx950):
     no __launch_bounds__      -> VGPR clamped ~64 -> spills big kernels
     __launch_bounds__(256)    -> allocator free (R8: 96 regs, zero spill) <- USE
     __launch_bounds__(256,N)  -> hard caps -> spills
   Shape-per-bottleneck ledger:
     edge: 2 rows/thread WINS (610 -> 475); node: 1 row/thread WINS
   Weight-path ledger:
     scalar s_load WINS; vector-path W2/W3 (R10) LOST 2x (VGPR 172, occ 12%)
   v2/packed ledger:
     R5 float2 spilled ONLY due to runtime indices (unroll 2). This version:
     FULL unroll, every index compile-time -> registers; h[j]+=w*x may form
     v_pk_fma_f32 (dual fp32 FMA, the 157-TF-rate instruction). */
#define W_EW1   0      /* [33][32] row-major: W1a[16][32], W1b[16][32], dir row */
#define W_EW1C  1056   /* [16][32] combined (W1a+W1b) for inplace branch */
#define W_EB1   1568
#define W_EW2   1600   /* [32][32] */
#define W_EB2   2624
#define W_EW3   2656   /* [32][32] */
#define W_EB3   3680
#define W_NW1   3712   /* [32][32] */
#define W_NB1   4736
#define W_NW2   4768   /* [32][32] */
#define W_NB2   5792
#define W_NW3   5824   /* [32][32] */
#define W_NB3   6848
#define W_AFF   6880   /* [3][64]: per branch scale[32] then shift[32] */

#define WS_EDGE_BYTE_OFF 65536ull
#define EOUT_BR_STRIDE   ((size_t)NT * 32u)   /* floats */

__device__ __forceinline__ float bf2f(uint16_t u) {
    union { uint u32; float f; } v; v.u32 = ((uint)u) << 16; return v.f;
}
__device__ __forceinline__ uint16_t f2bf(float f) {
    union { float f; uint u; } v; v.f = f;
    uint r = v.u + 0x7FFFu + ((v.u >> 16) & 1u);   // RTNE
    return (uint16_t)(r >> 16);
}

template <bool F32>
__device__ __forceinline__ float wv(const void* W, int i) {
    return F32 ? ((const float*)W)[i] : bf2f(((const uint16_t*)W)[i]);
}

template <bool F32>
__device__ __forceinline__ void loadrow16(const void* x, size_t elt, float* f) {
    if (F32) {
        const float4* q = (const float4*)((const float*)x + elt);
        float4 a = q[0], b = q[1], c = q[2], d = q[3];
        f[0]=a.x; f[1]=a.y; f[2]=a.z; f[3]=a.w;
        f[4]=b.x; f[5]=b.y; f[6]=b.z; f[7]=b.w;
        f[8]=c.x; f[9]=c.y; f[10]=c.z; f[11]=c.w;
        f[12]=d.x; f[13]=d.y; f[14]=d.z; f[15]=d.w;
    } else {
        const uint4* q = (const uint4*)((const uint16_t*)x + elt);
        uint4 a = q[0], b = q[1];
        uint w[8] = {a.x, a.y, a.z, a.w, b.x, b.y, b.z, b.w};
#pragma unroll
        for (int i = 0; i < 8; i++) {
            union { uint u; float f; } lo, hi;
            lo.u = w[i] << 16; hi.u = w[i] & 0xFFFF0000u;
            f[2*i] = lo.f; f[2*i+1] = hi.f;
        }
    }
}
template <bool F32>
__device__ __forceinline__ void loadrow32(const void* x, size_t elt, float* f) {
    loadrow16<F32>(x, elt, f); loadrow16<F32>(x, elt + 16, f + 16);
}
template <bool F32>
__device__ __forceinline__ void storerow32(void* out, size_t elt, const float* f) {
    if (F32) {
        float4* q = (float4*)((float*)out + elt);
#pragma unroll
        for (int i = 0; i < 8; i++)
            q[i] = make_float4(f[4*i], f[4*i+1], f[4*i+2], f[4*i+3]);
    } else {
        uint w[16];
#pragma unroll
        for (int i = 0; i < 16; i++)
            w[i] = (uint)f2bf(f[2*i]) | ((uint)f2bf(f[2*i+1]) << 16);
        uint4* q = (uint4*)((uint16_t*)out + elt);
        q[0] = make_uint4(w[0], w[1], w[2], w[3]);
        q[1] = make_uint4(w[4], w[5], w[6], w[7]);
        q[2] = make_uint4(w[8], w[9], w[10], w[11]);
        q[3] = make_uint4(w[12], w[13], w[14], w[15]);
    }
}

// ---- scalar dense (node recompute fallback only) ----
template <int K>
__device__ __forceinline__ void dense(const float* __restrict__ W, const float* in, float* h) {
#pragma unroll
    for (int i = 0; i < K; i++) {
        const float x = in[i];
        const float4* __restrict__ w4 = (const float4*)(W + i * 32);
#pragma unroll
        for (int j = 0; j < 8; j++) {
            float4 w = w4[j];
            h[4*j+0] = fmaf(w.x, x, h[4*j+0]);
            h[4*j+1] = fmaf(w.y, x, h[4*j+1]);
            h[4*j+2] = fmaf(w.z, x, h[4*j+2]);
            h[4*j+3] = fmaf(w.w, x, h[4*j+3]);
        }
    }
}
__device__ __forceinline__ void lrelu32(float* h) {
#pragma unroll
    for (int j = 0; j < 32; j++) h[j] = fmaxf(h[j], h[j] * SLOPE);
}

// ---- packed (v2) dense: accumulators are <2 x float>, ALL indices static ----
// Two row-streams, float inputs (layer 1).
template <int K>
__device__ __forceinline__ void dense2p_ff(const float* __restrict__ W,
    const float* inA, const float* inB, v2* hA, v2* hB)
{
#pragma unroll
    for (int i = 0; i < K; i++) {
        const float xa = inA[i], xb = inB[i];
        const v2* __restrict__ w2 = (const v2*)(W + i * 32);
#pragma unroll
        for (int j = 0; j < 16; j++) {
            v2 w = w2[j];
            hA[j] += w * xa;
            hB[j] += w * xb;
        }
    }
}
// Two row-streams, v2 inputs (layers 2/3). i is compile-time -> static extract.
template <int K>
__device__ __forceinline__ void dense2p_vv(const float* __restrict__ W,
    const v2* inA, const v2* inB, v2* hA, v2* hB)
{
#pragma unroll
    for (int i = 0; i < K; i++) {
        const float xa = inA[i >> 1][i & 1], xb = inB[i >> 1][i & 1];
        const v2* __restrict__ w2 = (const v2*)(W + i * 32);
#pragma unroll
        for (int j = 0; j < 16; j++) {
            v2 w = w2[j];
            hA[j] += w * xa;
            hB[j] += w * xb;
        }
    }
}
// Single stream, v2 input (node MLP).
template <int K>
__device__ __forceinline__ void densep_v(const float* __restrict__ W,
    const v2* in, v2* h)
{
#pragma unroll
    for (int i = 0; i < K; i++) {
        const float xi = in[i >> 1][i & 1];
        const v2* __restrict__ w2 = (const v2*)(W + i * 32);
#pragma unroll
        for (int j = 0; j < 16; j++) h[j] += w2[j] * xi;
    }
}
__device__ __forceinline__ void lrelu16p(v2* h) {
#pragma unroll
    for (int j = 0; j < 16; j++) {
        v2 s = h[j] * SLOPE;
        h[j][0] = fmaxf(h[j][0], s[0]);
        h[j][1] = fmaxf(h[j][1], s[1]);
    }
}

// One edge branch, ONE row (node recompute fallback only).
template <bool INPLACE>
__device__ __forceinline__ void edge_mlp(
    const float* __restrict__ wts,
    const float* xt, const float* xn, float dir, float* o)
{
    const float* __restrict__ W1  = wts + W_EW1;
    const float* __restrict__ W1c = wts + W_EW1C;
    const float* __restrict__ B1  = wts + W_EB1;
    const float* __restrict__ W2  = wts + W_EW2;
    const float* __restrict__ B2  = wts + W_EB2;
    const float* __restrict__ W3  = wts + W_EW3;
    const float* __restrict__ B3  = wts + W_EB3;

    float h1[32];
#pragma unroll
    for (int j = 0; j < 32; j++) h1[j] = fmaf(dir, W1[1024 + j], B1[j]);
    if (INPLACE) {
        dense<16>(W1c, xt, h1);
    } else {
        dense<16>(W1, xt, h1);
        dense<16>(W1 + 512, xn, h1);
    }
    lrelu32(h1);
    float h2[32];
#pragma unroll
    for (int j = 0; j < 32; j++) h2[j] = B2[j];
    dense<32>(W2, h1, h2);
    lrelu32(h2);
#pragma unroll
    for (int j = 0; j < 32; j++) o[j] = B3[j];
    dense<32>(W3, h2, o);
}

// One edge branch, TWO adjacent rows, packed accumulators.
// MODE 0 inplace: hA=W1c.xA, hB=W1c.xB
// MODE 1 fwd:     hA=W1a.xA+W1b.xE (+wd), hB=W1a.xB+W1b.xA   (xE = x_{r0-1})
// MODE 2 bwd:     hA=W1a.xA+W1b.xB (-wd), hB=W1a.xB+W1b.xE   (xE = x_{r0+2})
template <int MODE>
__device__ __forceinline__ void edge2_mlp(
    const float* __restrict__ wts,
    const float* xA, const float* xB, const float* xE,
    v2* oA, v2* oB)
{
    const float* __restrict__ W1a = wts + W_EW1;
    const float* __restrict__ W1b = wts + W_EW1 + 512;
    const v2*    __restrict__ WDv = (const v2*)(wts + W_EW1 + 1024);
    const float* __restrict__ W1c = wts + W_EW1C;
    const v2*    __restrict__ B1v = (const v2*)(wts + W_EB1);
    const float* __restrict__ W2  = wts + W_EW2;
    const v2*    __restrict__ B2v = (const v2*)(wts + W_EB2);
    const float* __restrict__ W3  = wts + W_EW3;
    const v2*    __restrict__ B3v = (const v2*)(wts + W_EB3);
    const float dir = (MODE == 0) ? 0.f : (MODE == 1) ? 1.f : -1.f;

    v2 hA[16], hB[16];
#pragma unroll
    for (int j = 0; j < 16; j++) {
        v2 v = B1v[j] + WDv[j] * dir;
        hA[j] = v; hB[j] = v;
    }
    if (MODE == 0) {
        dense2p_ff<16>(W1c, xA, xB, hA, hB);
    } else if (MODE == 1) {
        dense2p_ff<16>(W1a, xA, xB, hA, hB);
        dense2p_ff<16>(W1b, xE, xA, hA, hB);
    } else {
        dense2p_ff<16>(W1a, xA, xB, hA, hB);
        dense2p_ff<16>(W1b, xB, xE, hA, hB);
    }
    lrelu16p(hA); lrelu16p(hB);

    v2 gA[16], gB[16];
#pragma unroll
    for (int j = 0; j < 16; j++) { v2 b = B2v[j]; gA[j] = b; gB[j] = b; }
    dense2p_vv<32>(W2, hA, hB, gA, gB);
    lrelu16p(gA); lrelu16p(gB);

#pragma unroll
    for (int j = 0; j < 16; j++) { v2 b = B3v[j]; oA[j] = b; oB[j] = b; }
    dense2p_vv<32>(W3, gA, gB, oA, oB);
}

// Packed in-place reduce-scatter butterfly: sums v[j] and v[j]^2 over 64 lanes.
// DESTROYS v. lane L<32 -> sum of channel L; lane L>=32 -> sumsq of ch L-32.
__device__ __forceinline__ float stats_reduce64(float* v, int lane) {
    const bool hi = lane >= 32;
#pragma unroll
    for (int j = 0; j < 32; j++) {
        float s = v[j], q = v[j] * v[j];
        float r = __shfl_xor(hi ? s : q, 32, 64);
        v[j] = (hi ? q : s) + r;
    }
#pragma unroll
    for (int m = 16; m >= 1; m >>= 1) {
        const bool b = (lane & m) != 0;
#pragma unroll
        for (int j = 0; j < m; j++) {
            float r = __shfl_xor(b ? v[j] : v[j + m], m, 64);
            v[j] = (b ? v[j + m] : v[j]) + r;
        }
    }
    return v[0];
}
// Two-row variant: folds A+B / A^2+B^2 in the first sweep. DESTROYS a.
__device__ __forceinline__ float stats_reduce64_pair(float* a, const float* b, int lane) {
    const bool hi = lane >= 32;
#pragma unroll
    for (int j = 0; j < 32; j++) {
        float s = a[j] + b[j];
        float q = a[j] * a[j] + b[j] * b[j];
        float r = __shfl_xor(hi ? s : q, 32, 64);
        a[j] = (hi ? q : s) + r;
    }
#pragma unroll
    for (int m = 16; m >= 1; m >>= 1) {
        const bool bb = (lane & m) != 0;
#pragma unroll
        for (int j = 0; j < m; j++) {
            float r = __shfl_xor(bb ? a[j] : a[j + m], m, 64);
            a[j] = (bb ? a[j + m] : a[j]) + r;
        }
    }
    return a[0];
}

// ---------------- prep: dtype detect + fp32 weight conversion ----------------
__global__ void prep_kernel(
    const uint* __restrict__ x,
    const void* __restrict__ eW1, const void* __restrict__ eb1,
    const void* __restrict__ eW2, const void* __restrict__ eb2,
    const void* __restrict__ eW3, const void* __restrict__ eb3,
    const void* __restrict__ nW1, const void* __restrict__ nb1,
    const void* __restrict__ nW2, const void* __restrict__ nb2,
    const void* __restrict__ nW3, const void* __restrict__ nb3,
    int* __restrict__ flag, float* __restrict__ wts)
{
    __shared__ int cnt;
    const int tid = threadIdx.x;
    if (tid == 0) cnt = 0;
    __syncthreads();
    if (tid < 64) {
        uint w = x[tid];
        uint e = (w >> 7) & 0xFFu;
        if (e >= 110u && e <= 134u) atomicAdd(&cnt, 1);
    }
    __syncthreads();
    const bool f32 = (cnt < 32);
    if (tid == 0) flag[0] = f32 ? 1 : 0;
    auto rd = [&](const void* p, int i) -> float {
        return f32 ? ((const float*)p)[i] : bf2f(((const uint16_t*)p)[i]);
    };
    for (int i = tid; i < 1056; i += 256) wts[W_EW1 + i] = rd(eW1, i);
    for (int i = tid; i < 512;  i += 256) wts[W_EW1C + i] = rd(eW1, i) + rd(eW1, 512 + i);
    for (int i = tid; i < 1024; i += 256) {
        wts[W_EW2 + i] = rd(eW2, i); wts[W_EW3 + i] = rd(eW3, i);
        wts[W_NW1 + i] = rd(nW1, i); wts[W_NW2 + i] = rd(nW2, i); wts[W_NW3 + i] = rd(nW3, i);
    }
    if (tid < 32) {
        wts[W_EB1 + tid] = rd(eb1, tid); wts[W_EB2 + tid] = rd(eb2, tid); wts[W_EB3 + tid] = rd(eb3, tid);
        wts[W_NB1 + tid] = rd(nb1, tid); wts[W_NB2 + tid] = rd(nb2, tid); wts[W_NB3 + tid] = rd(nb3, tid);
    }
}

// ------- pass 1: one branch per block, 2 rows per thread, XCD-interleaved -------
template <bool F32, bool STORE>
__global__ __launch_bounds__(256) void edge_branch2_kernel(
    const void* __restrict__ x, const float* __restrict__ wts,
    const int* __restrict__ flag, float* __restrict__ gstats /*192*/,
    float* __restrict__ eout)
{
    if ((flag[0] != 0) != F32) return;
    __shared__ float sSt[64];
    const int tid = threadIdx.x;
    const int lane = tid & 63;
    const uint bid = blockIdx.x;           // 0 .. 3*NT/512-1
    const uint unit = bid / 24u;
    const uint inner = bid % 24u;
    const int  by = (int)(inner >> 3);     // branch: 0 inpl, 1 fwd, 2 bwd
    const uint bx = unit * 8u + (inner & 7u);
    if (tid < 64) sSt[tid] = 0.f;
    __syncthreads();

    const uint r0 = bx * 512u + (uint)tid * 2u;   // even row; rows r0, r0+1
    const uint t0 = r0 & 511u;                     // even, <= 510

    float xA[16], xB[16];
    loadrow16<F32>(x, (size_t)r0 << 4, xA);
    loadrow16<F32>(x, (size_t)(r0 + 1u) << 4, xB);

    v2 oA[16], oB[16];
    float vfA = 1.f, vfB = 1.f;
    if (by == 0) {
        edge2_mlp<0>(wts, xA, xB, xA, oA, oB);
    } else if (by == 1) {
        const uint rp = (t0 > 0u) ? r0 - 1u : r0;
        float xP[16]; loadrow16<F32>(x, (size_t)rp << 4, xP);
        edge2_mlp<1>(wts, xA, xB, xP, oA, oB);
        vfA = (t0 > 0u) ? 1.f : 0.f;
    } else {
        const uint rn = (t0 != 510u) ? r0 + 2u : r0 + 1u;
        float xN[16]; loadrow16<F32>(x, (size_t)rn << 4, xN);
        edge2_mlp<2>(wts, xA, xB, xN, oA, oB);
        vfB = (t0 != 510u) ? 1.f : 0.f;
    }

    if (STORE) {
        float4* q = (float4*)(eout + (size_t)by * EOUT_BR_STRIDE + (size_t)r0 * 32u);
#pragma unroll
        for (int k = 0; k < 8; k++)
            q[k] = make_float4(oA[2*k][0], oA[2*k][1], oA[2*k+1][0], oA[2*k+1][1]);
#pragma unroll
        for (int k = 0; k < 8; k++)
            q[8 + k] = make_float4(oB[2*k][0], oB[2*k][1], oB[2*k+1][0], oB[2*k+1][1]);
    }
    float fA[32], fB[32];
#pragma unroll
    for (int j = 0; j < 16; j++) {
        fA[2*j] = oA[j][0] * vfA; fA[2*j+1] = oA[j][1] * vfA;
        fB[2*j] = oB[j][0] * vfB; fB[2*j+1] = oB[j][1] * vfB;
    }
    atomicAdd(&sSt[lane], stats_reduce64_pair(fA, fB, lane));
    __syncthreads();
    if (tid < 64) atomicAdd(&gstats[by * 64 + tid], sSt[tid]);
}

// ------------- tiny: edge BN affine coefficients -> workspace (SGPR path) -------------
template <bool F32>
__global__ void edge_affine_kernel(
    const float* __restrict__ gstats_edge,
    const void* __restrict__ egamma, const void* __restrict__ ebeta,
    const int* __restrict__ flag, float* __restrict__ wts_aff)
{
    if ((flag[0] != 0) != F32) return;
    const int tid = threadIdx.x;
    if (tid < 32) {
        float g = wv<F32>(egamma, tid), be = wv<F32>(ebeta, tid);
#pragma unroll
        for (int br = 0; br < 3; br++) {
            float cnt = (br == 0) ? (float)NT : (float)NTM;
            float s = gstats_edge[br * 64 + tid], q = gstats_edge[br * 64 + 32 + tid];
            float mu = s / cnt;
            float var = q / cnt - mu * mu;
            float sc = g * rsqrtf(var + BN_EPS);
            wts_aff[W_AFF + br * 64 + tid] = sc;
            wts_aff[W_AFF + br * 64 + 32 + tid] = be - mu * sc;
        }
    }
}

// -------- pass 2 (stored): ONE row/thread: load branch outputs, affine, node MLP --------
template <bool F32>
__global__ __launch_bounds__(256) void node_store_kernel(
    const float* __restrict__ eout, const float* __restrict__ wts,
    const int* __restrict__ flag, float* __restrict__ gstats_node,
    void* __restrict__ out)
{
    if ((flag[0] != 0) != F32) return;
    __shared__ float sSt[64];
    const int tid = threadIdx.x;
    const int lane = tid & 63;
    if (tid < 64) sSt[tid] = 0.f;
    __syncthreads();

    const v2* __restrict__ AFFv = (const v2*)(wts + W_AFF);  // [6][16] v2
    const uint r = blockIdx.x * 256u + (uint)tid;
    const uint t = r & 511u;
    const float vf0 = (t > 0u) ? 1.f : 0.f;
    const float vf1 = (t < 511u) ? 1.f : 0.f;

    float ob[32];
    v2 agg[16];
    loadrow32<true>((const void*)eout, (size_t)r * 32u, ob);
#pragma unroll
    for (int k = 0; k < 16; k++) {
        v2 o; o[0] = ob[2*k]; o[1] = ob[2*k+1];
        agg[k] = AFFv[k] * o + AFFv[16 + k];
    }
    loadrow32<true>((const void*)eout, EOUT_BR_STRIDE + (size_t)r * 32u, ob);
#pragma unroll
    for (int k = 0; k < 16; k++) {
        v2 o; o[0] = ob[2*k]; o[1] = ob[2*k+1];
        agg[k] += (AFFv[32 + k] * o + AFFv[48 + k]) * vf0;
    }
    loadrow32<true>((const void*)eout, 2u * EOUT_BR_STRIDE + (size_t)r * 32u, ob);
#pragma unroll
    for (int k = 0; k < 16; k++) {
        v2 o; o[0] = ob[2*k]; o[1] = ob[2*k+1];
        agg[k] += (AFFv[64 + k] * o + AFFv[80 + k]) * vf1;
    }

    const float* __restrict__ NW1 = wts + W_NW1;
    const float* __restrict__ NW2 = wts + W_NW2;
    const float* __restrict__ NW3 = wts + W_NW3;
    const v2* __restrict__ NB1v = (const v2*)(wts + W_NB1);
    const v2* __restrict__ NB2v = (const v2*)(wts + W_NB2);
    const v2* __restrict__ NB3v = (const v2*)(wts + W_NB3);

    v2 g1[16];
#pragma unroll
    for (int k = 0; k < 16; k++) g1[k] = NB1v[k];
    densep_v<32>(NW1, agg, g1);
    lrelu16p(g1);
    v2 g2[16];
#pragma unroll
    for (int k = 0; k < 16; k++) g2[k] = NB2v[k];
    densep_v<32>(NW2, g1, g2);
    lrelu16p(g2);
    v2 g3[16];
#pragma unroll
    for (int k = 0; k < 16; k++) g3[k] = NB3v[k];
    densep_v<32>(NW3, g2, g3);

    float gf[32];
#pragma unroll
    for (int k = 0; k < 16; k++) { gf[2*k] = g3[k][0]; gf[2*k+1] = g3[k][1]; }
    storerow32<F32>(out, (size_t)r * 32u, gf);
    atomicAdd(&sSt[lane], stats_reduce64(gf, lane));   // destroys gf (already stored)
    __syncthreads();
    if (tid < 64) atomicAdd(&gstats_node[tid], sSt[tid]);
}

// -------- pass 2 (fallback, ws too small): recompute branches, 1 row, scalar --------
template <bool F32>
__global__ __launch_bounds__(256) void node_recompute_kernel(
    const void* __restrict__ x, const float* __restrict__ wts,
    const int* __restrict__ flag, float* __restrict__ gstats_node,
    void* __restrict__ out)
{
    if ((flag[0] != 0) != F32) return;
    __shared__ float sSt[64];
    const int tid = threadIdx.x;
    const int lane = tid & 63;
    if (tid < 64) sSt[tid] = 0.f;
    __syncthreads();

    const float* __restrict__ AFF = wts + W_AFF;
    const uint r = blockIdx.x * 256u + (uint)tid;
    const uint t = r & 511u;
    float xt[16]; loadrow16<F32>(x, (size_t)r << 4, xt);
    float agg[32], o[32];

    edge_mlp<true>(wts, xt, xt, 0.f, o);
#pragma unroll
    for (int j = 0; j < 32; j++) agg[j] = fmaf(AFF[j], o[j], AFF[32 + j]);
    {
        const float vf = (t > 0u) ? 1.f : 0.f;
        const uint rn = (t > 0u) ? r - 1u : r;
        float xn[16]; loadrow16<F32>(x, (size_t)rn << 4, xn);
        edge_mlp<false>(wts, xt, xn, 1.f, o);
#pragma unroll
        for (int j = 0; j < 32; j++) agg[j] += vf * fmaf(AFF[64 + j], o[j], AFF[96 + j]);
    }
    {
        const float vf = (t < 511u) ? 1.f : 0.f;
        const uint rn = (t < 511u) ? r + 1u : r;
        float xn[16]; loadrow16<F32>(x, (size_t)rn << 4, xn);
        edge_mlp<false>(wts, xt, xn, -1.f, o);
#pragma unroll
        for (int j = 0; j < 32; j++) agg[j] += vf * fmaf(AFF[128 + j], o[j], AFF[160 + j]);
    }

    const float* __restrict__ NW1 = wts + W_NW1;
    const float* __restrict__ NW2 = wts + W_NW2;
    const float* __restrict__ NW3 = wts + W_NW3;
    const float* __restrict__ NB1 = wts + W_NB1;
    const float* __restrict__ NB2 = wts + W_NB2;
    const float* __restrict__ NB3 = wts + W_NB3;

    float g1[32];
#pragma unroll
    for (int j = 0; j < 32; j++) g1[j] = NB1[j];
    dense<32>(NW1, agg, g1);
    lrelu32(g1);
    float g2[32];
#pragma unroll
    for (int j = 0; j < 32; j++) g2[j] = NB2[j];
    dense<32>(NW2, g1, g2);
    lrelu32(g2);
    float g3[32];
#pragma unroll
    for (int j = 0; j < 32; j++) g3[j] = NB3[j];
    dense<32>(NW3, g2, g3);

    storerow32<F32>(out, (size_t)r * 32u, g3);
    atomicAdd(&sSt[lane], stats_reduce64(g3, lane));
    __syncthreads();
    if (tid < 64) atomicAdd(&gstats_node[tid], sSt[tid]);
}

// ---------------- pass 3: in-place node BN affine ----------------
template <bool F32>
__global__ __launch_bounds__(256) void finalize_kernel(
    const float* __restrict__ gstats_node,
    const void* __restrict__ ngamma, const void* __restrict__ nbeta,
    const int* __restrict__ flag, void* __restrict__ out)
{
    if ((flag[0] != 0) != F32) return;
    __shared__ float sc[32], sh[32];
    const int tid = threadIdx.x;
    if (tid < 32) {
        float s = gstats_node[tid], q = gstats_node[32 + tid];
        float mu = s / (float)NT;
        float var = q / (float)NT - mu * mu;
        float k = wv<F32>(ngamma, tid) * rsqrtf(var + BN_EPS);
        sc[tid] = k; sh[tid] = wv<F32>(nbeta, tid) - mu * k;
    }
    __syncthreads();
    const uint r = blockIdx.x * 256u + (uint)tid;
    float v[32]; loadrow32<F32>(out, (size_t)r * 32u, v);
    float o[32];
#pragma unroll
    for (int j = 0; j < 32; j++) o[j] = fmaf(sc[j], v[j], sh[j]);
    storerow32<F32>(out, (size_t)r * 32u, o);
}

extern "C" void kernel_launch(void* const* d_in, const int* in_sizes, int n_in,
                              void* d_out, int out_size, void* d_ws, size_t ws_size,
                              hipStream_t stream) {
    const void* x   = d_in[0];
    const void* eW1 = d_in[1]; const void* eb1 = d_in[2];
    const void* eW2 = d_in[3]; const void* eb2 = d_in[4];
    const void* eW3 = d_in[5]; const void* eb3 = d_in[6];
    const void* eg  = d_in[7]; const void* ebt = d_in[8];
    const void* nW1 = d_in[9]; const void* nb1 = d_in[10];
    const void* nW2 = d_in[11]; const void* nb2 = d_in[12];
    const void* nW3 = d_in[13]; const void* nb3 = d_in[14];
    const void* ng  = d_in[15]; const void* nbt = d_in[16];

    float* wts   = (float*)d_ws;                       // fp32 weights + affine
    float* stats = (float*)((char*)d_ws + 32768);      // [0..191] edge, [192..255] node
    int* flag    = (int*)((char*)d_ws + 36864);        // dtype flag: 1 = fp32, 0 = bf16
    float* eout  = (float*)((char*)d_ws + WS_EDGE_BYTE_OFF);

    const size_t need = WS_EDGE_BYTE_OFF + 3ull * (size_t)NT * 32ull * sizeof(float);
    const bool stored = (ws_size >= need);

    hipMemsetAsync((char*)d_ws + 32768, 0, 8192, stream);
    prep_kernel<<<dim3(1), dim3(256), 0, stream>>>((const uint*)x,
        eW1, eb1, eW2, eb2, eW3, eb3, nW1, nb1, nW2, nb2, nW3, nb3, flag, wts);

    dim3 blk(256);
    dim3 egrid(3 * (NT / 512));      // edge: 2 rows/thread
    dim3 fgrid(NT / 256);            // node/finalize: 1 row/thread
    if (stored) {
        edge_branch2_kernel<true,  true><<<egrid, blk, 0, stream>>>(x, wts, flag, stats, eout);
        edge_branch2_kernel<false, true><<<egrid, blk, 0, stream>>>(x, wts, flag, stats, eout);
    } else {
        edge_branch2_kernel<true,  false><<<egrid, blk, 0, stream>>>(x, wts, flag, stats, eout);
        edge_branch2_kernel<false, false><<<egrid, blk, 0, stream>>>(x, wts, flag, stats, eout);
    }
    edge_affine_kernel<true><<<dim3(1), dim3(64), 0, stream>>>(stats, eg, ebt, flag, wts);
    edge_affine_kernel<false><<<dim3(1), dim3(64), 0, stream>>>(stats, eg, ebt, flag, wts);
    if (stored) {
        node_store_kernel<true><<<fgrid, blk, 0, stream>>>(eout, wts, flag, stats + 192, d_out);
        node_store_kernel<false><<<fgrid, blk, 0, stream>>>(eout, wts, flag, stats + 192, d_out);
    } else {
        node_recompute_kernel<true><<<fgrid, blk, 0, stream>>>(x, wts, flag, stats + 192, d_out);
        node_recompute_kernel<false><<<fgrid, blk, 0, stream>>>(x, wts, flag, stats + 192, d_out);
    }
    finalize_kernel<true><<<fgrid, blk, 0, stream>>>(stats + 192, ng, nbt, flag, d_out);
    finalize_kernel<false><<<fgrid, blk, 0, stream>>>(stats + 192, ng, nbt, flag, d_out);
}